// Round 8
// baseline (88.996 us; speedup 1.0000x reference)
//
#include <hip/hip_runtime.h>
#include <math.h>

#define NKV    8
#define NREP   4
#define NH     32
#define BATCH  8
#define D      128
#define SEQ    4096
#define PSTRIDE 130         // 128 o + m + l per (pair,chunk,rep)

// ---------------------------------------------------------------------------
// Primary kernel: 64-row chunk per block, 128 threads (2 waves), no K/V LDS
// staging — pure streaming with maximal wave-level parallelism.
// grid (64 pairs, 64 chunks). Wave w owns rows [w*32, w*32+32).
// ---------------------------------------------------------------------------
__global__ __launch_bounds__(128, 6) void attn_partial64(
    const int*   __restrict__ input_pos,
    const float* __restrict__ q,
    const float* __restrict__ knew,
    const float* __restrict__ vnew,
    const float* __restrict__ kcache,
    const float* __restrict__ vcache,
    const float* __restrict__ mask,
    float*       __restrict__ ws)
{
    const int pair = blockIdx.x;      // g*8 + b
    const int c    = blockIdx.y;
    const int g    = pair >> 3;
    const int b    = pair & 7;
    const int t    = threadIdx.x;
    const int w    = t >> 6;          // wave id (0,1)
    const int lane = t & 63;
    const int p4   = lane >> 4;       // row within 4-row group (scores)
    const int l16  = lane & 15;       // 8-float segment (scores)
    const int vh   = lane >> 5;       // row parity (PV)
    const int l32  = lane & 31;       // float4 d-slice (PV)
    const int pos  = input_pos[0];

    __shared__ float4 sc4[64];            // per-row 4-rep scores -> e-values (1KB)
    __shared__ float  opart[2][NREP][D];  // per-wave PV partials (4KB)

    const float  scale  = 0.08838834764831845f;   // 1/sqrt(128)
    const size_t kvbase = (size_t)(g * BATCH + b) * SEQ * D;
    const float* kbase  = kcache + kvbase;
    const float* vbase  = vcache + kvbase;
    const float* mrow   = mask + (size_t)pos * SEQ;
    const float* knewr  = knew + (size_t)(g * BATCH + b) * D;
    const float* vnewr  = vnew + (size_t)(g * BATCH + b) * D;
    const int    s0     = c * 64;

    // q fragments for all 4 reps (8 floats each = 32 VGPRs)
    float4 qv[NREP][2];
    #pragma unroll
    for (int r = 0; r < NREP; ++r) {
        const float4* qr = (const float4*)(q + ((size_t)(g * NREP + r) * BATCH + b) * D
                                           + l16 * 8);
        qv[r][0] = qr[0];
        qv[r][1] = qr[1];
    }

    // ---- scores: wave w rows [w*32, w*32+32), 8 iters x 4 rows ----
    #pragma unroll
    for (int i = 0; i < 8; ++i) {
        const int rl = w * 32 + i * 4 + p4;        // 0..63
        const int s  = s0 + rl;
        const float* krow = (s == pos) ? knewr : (kbase + (size_t)s * D);
        const float4* k4  = (const float4*)(krow + l16 * 8);
        const float4 k0 = k4[0], k1 = k4[1];
        float acc[NREP];
        #pragma unroll
        for (int r = 0; r < NREP; ++r) {
            float a;
            a = k0.x * qv[r][0].x;
            a = fmaf(k0.y, qv[r][0].y, a);
            a = fmaf(k0.z, qv[r][0].z, a);
            a = fmaf(k0.w, qv[r][0].w, a);
            a = fmaf(k1.x, qv[r][1].x, a);
            a = fmaf(k1.y, qv[r][1].y, a);
            a = fmaf(k1.z, qv[r][1].z, a);
            a = fmaf(k1.w, qv[r][1].w, a);
            acc[r] = a;
        }
        #pragma unroll
        for (int off = 1; off < 16; off <<= 1) {
            #pragma unroll
            for (int r = 0; r < NREP; ++r)
                acc[r] += __shfl_xor(acc[r], off);
        }
        if (l16 == 0) {
            const float mval = mrow[s];
            sc4[rl] = make_float4(fmaf(acc[0], scale, mval),
                                  fmaf(acc[1], scale, mval),
                                  fmaf(acc[2], scale, mval),
                                  fmaf(acc[3], scale, mval));
        }
    }
    __syncthreads();

    // ---- softmax over 64 rows (both waves duplicate; identical results) ----
    float4 sv = sc4[lane];            // row = lane
    float4 mm = sv;
    #pragma unroll
    for (int off = 1; off < 64; off <<= 1) {
        mm.x = fmaxf(mm.x, __shfl_xor(mm.x, off));
        mm.y = fmaxf(mm.y, __shfl_xor(mm.y, off));
        mm.z = fmaxf(mm.z, __shfl_xor(mm.z, off));
        mm.w = fmaxf(mm.w, __shfl_xor(mm.w, off));
    }
    float4 ev;
    ev.x = __expf(sv.x - mm.x);
    ev.y = __expf(sv.y - mm.y);
    ev.z = __expf(sv.z - mm.z);
    ev.w = __expf(sv.w - mm.w);
    if (w == 0) sc4[lane] = ev;
    float4 LL = ev;
    #pragma unroll
    for (int off = 1; off < 64; off <<= 1) {
        LL.x += __shfl_xor(LL.x, off);
        LL.y += __shfl_xor(LL.y, off);
        LL.z += __shfl_xor(LL.z, off);
        LL.w += __shfl_xor(LL.w, off);
    }
    __syncthreads();

    // ---- PV: wave w rows [w*32, w*32+32), 16 iters of row-pairs ----
    float4 oacc[NREP];
    #pragma unroll
    for (int r = 0; r < NREP; ++r) oacc[r] = make_float4(0.f, 0.f, 0.f, 0.f);

    #pragma unroll
    for (int it = 0; it < 16; ++it) {
        const int rl = w * 32 + it * 2 + vh;
        const int s  = s0 + rl;
        const float* vrow = (s == pos) ? vnewr : (vbase + (size_t)s * D);
        const float4 vv  = *(const float4*)(vrow + l32 * 4);
        const float4 pr  = sc4[rl];   // broadcast (2 addrs per wave)
        oacc[0].x = fmaf(pr.x, vv.x, oacc[0].x);
        oacc[0].y = fmaf(pr.x, vv.y, oacc[0].y);
        oacc[0].z = fmaf(pr.x, vv.z, oacc[0].z);
        oacc[0].w = fmaf(pr.x, vv.w, oacc[0].w);
        oacc[1].x = fmaf(pr.y, vv.x, oacc[1].x);
        oacc[1].y = fmaf(pr.y, vv.y, oacc[1].y);
        oacc[1].z = fmaf(pr.y, vv.z, oacc[1].z);
        oacc[1].w = fmaf(pr.y, vv.w, oacc[1].w);
        oacc[2].x = fmaf(pr.z, vv.x, oacc[2].x);
        oacc[2].y = fmaf(pr.z, vv.y, oacc[2].y);
        oacc[2].z = fmaf(pr.z, vv.z, oacc[2].z);
        oacc[2].w = fmaf(pr.z, vv.w, oacc[2].w);
        oacc[3].x = fmaf(pr.w, vv.x, oacc[3].x);
        oacc[3].y = fmaf(pr.w, vv.y, oacc[3].y);
        oacc[3].z = fmaf(pr.w, vv.z, oacc[3].z);
        oacc[3].w = fmaf(pr.w, vv.w, oacc[3].w);
    }
    #pragma unroll
    for (int r = 0; r < NREP; ++r) {
        oacc[r].x += __shfl_xor(oacc[r].x, 32);
        oacc[r].y += __shfl_xor(oacc[r].y, 32);
        oacc[r].z += __shfl_xor(oacc[r].z, 32);
        oacc[r].w += __shfl_xor(oacc[r].w, 32);
    }
    if (vh == 0) {
        #pragma unroll
        for (int r = 0; r < NREP; ++r)
            *(float4*)&opart[w][r][l32 * 4] = oacc[r];
    }
    __syncthreads();

    // ---- combine the 2 wave partials, write workspace ----
    #pragma unroll
    for (int ii = 0; ii < 4; ++ii) {
        int idx = t + ii * 128;       // 0..511 -> (r, d)
        int r   = idx >> 7;
        int d   = idx & 127;
        float sum = opart[0][r][d] + opart[1][r][d];
        size_t base = (((size_t)pair * 64 + c) * NREP + r) * PSTRIDE;
        ws[base + d] = sum;
    }
    if (t == 0) {
        size_t base = (((size_t)pair * 64 + c) * NREP) * PSTRIDE;
        ws[base + 128] = mm.x;               ws[base + 129] = LL.x;
        ws[base + PSTRIDE + 128] = mm.y;     ws[base + PSTRIDE + 129] = LL.y;
        ws[base + 2 * PSTRIDE + 128] = mm.z; ws[base + 2 * PSTRIDE + 129] = LL.z;
        ws[base + 3 * PSTRIDE + 128] = mm.w; ws[base + 3 * PSTRIDE + 129] = LL.w;
    }
}

// ---------------------------------------------------------------------------
// Fallback 1 (proven R5 kernel): 128-row chunk, 256 threads, CHUNKS=32.
// ---------------------------------------------------------------------------
__global__ __launch_bounds__(256, 4) void attn_partial128(
    const int*   __restrict__ input_pos,
    const float* __restrict__ q,
    const float* __restrict__ knew,
    const float* __restrict__ vnew,
    const float* __restrict__ kcache,
    const float* __restrict__ vcache,
    const float* __restrict__ mask,
    float*       __restrict__ ws)
{
    const int pair = blockIdx.x;
    const int c    = blockIdx.y;
    const int g    = pair >> 3;
    const int b    = pair & 7;
    const int t    = threadIdx.x;
    const int w    = t >> 6;
    const int lane = t & 63;
    const int p4   = lane >> 4;
    const int l16  = lane & 15;
    const int pos  = input_pos[0];

    __shared__ float sc[NREP][128];
    __shared__ float ml[NREP][2];
    __shared__ float opart[4][NREP][D];

    const float  scale  = 0.08838834764831845f;
    const size_t kvbase = (size_t)(g * BATCH + b) * SEQ * D;
    const float* kbase  = kcache + kvbase;
    const float* vbase  = vcache + kvbase;
    const float* mrow   = mask + (size_t)pos * SEQ;
    const float* knewr  = knew + (size_t)(g * BATCH + b) * D;
    const float* vnewr  = vnew + (size_t)(g * BATCH + b) * D;
    const int    s0     = c * 128;
    const int    rowbase = w * 32;

    float4 qv[NREP][2];
    #pragma unroll
    for (int r = 0; r < NREP; ++r) {
        const float4* qr = (const float4*)(q + ((size_t)(g * NREP + r) * BATCH + b) * D
                                           + l16 * 8);
        qv[r][0] = qr[0];
        qv[r][1] = qr[1];
    }

    #pragma unroll
    for (int i = 0; i < 8; ++i) {
        const int sl = rowbase + i * 4 + p4;
        const int s  = s0 + sl;
        const float* krow = (s == pos) ? knewr : (kbase + (size_t)s * D);
        const float4* k4  = (const float4*)(krow + l16 * 8);
        const float4 k0 = k4[0], k1 = k4[1];
        float acc[NREP];
        #pragma unroll
        for (int r = 0; r < NREP; ++r) {
            float a;
            a = k0.x * qv[r][0].x;
            a = fmaf(k0.y, qv[r][0].y, a);
            a = fmaf(k0.z, qv[r][0].z, a);
            a = fmaf(k0.w, qv[r][0].w, a);
            a = fmaf(k1.x, qv[r][1].x, a);
            a = fmaf(k1.y, qv[r][1].y, a);
            a = fmaf(k1.z, qv[r][1].z, a);
            a = fmaf(k1.w, qv[r][1].w, a);
            acc[r] = a;
        }
        #pragma unroll
        for (int off = 1; off < 16; off <<= 1) {
            #pragma unroll
            for (int r = 0; r < NREP; ++r)
                acc[r] += __shfl_xor(acc[r], off);
        }
        if (l16 == 0) {
            const float mval = mrow[s];
            #pragma unroll
            for (int r = 0; r < NREP; ++r)
                sc[r][sl] = fmaf(acc[r], scale, mval);
        }
    }
    __syncthreads();

    {
        const int r = w;
        float v0 = sc[r][lane];
        float v1 = sc[r][lane + 64];
        float m  = fmaxf(v0, v1);
        #pragma unroll
        for (int off = 1; off < 64; off <<= 1)
            m = fmaxf(m, __shfl_xor(m, off));
        float e0 = __expf(v0 - m);
        float e1 = __expf(v1 - m);
        sc[r][lane]      = e0;
        sc[r][lane + 64] = e1;
        float l = e0 + e1;
        #pragma unroll
        for (int off = 1; off < 64; off <<= 1)
            l += __shfl_xor(l, off);
        if (lane == 0) { ml[r][0] = m; ml[r][1] = l; }
    }
    __syncthreads();

    const int half = lane >> 5;
    const int l32  = lane & 31;
    float4 oacc[NREP];
    #pragma unroll
    for (int r = 0; r < NREP; ++r) oacc[r] = make_float4(0.f, 0.f, 0.f, 0.f);

    #pragma unroll
    for (int it = 0; it < 16; ++it) {
        const int sl = rowbase + it * 2 + half;
        const int s  = s0 + sl;
        const float* vrow = (s == pos) ? vnewr : (vbase + (size_t)s * D);
        const float4 v4 = *(const float4*)(vrow + l32 * 4);
        #pragma unroll
        for (int r = 0; r < NREP; ++r) {
            const float pr = sc[r][sl];
            oacc[r].x = fmaf(pr, v4.x, oacc[r].x);
            oacc[r].y = fmaf(pr, v4.y, oacc[r].y);
            oacc[r].z = fmaf(pr, v4.z, oacc[r].z);
            oacc[r].w = fmaf(pr, v4.w, oacc[r].w);
        }
    }
    #pragma unroll
    for (int r = 0; r < NREP; ++r) {
        oacc[r].x += __shfl_xor(oacc[r].x, 32);
        oacc[r].y += __shfl_xor(oacc[r].y, 32);
        oacc[r].z += __shfl_xor(oacc[r].z, 32);
        oacc[r].w += __shfl_xor(oacc[r].w, 32);
    }
    if (half == 0) {
        #pragma unroll
        for (int r = 0; r < NREP; ++r)
            *(float4*)&opart[w][r][l32 * 4] = oacc[r];
    }
    __syncthreads();

    #pragma unroll
    for (int ii = 0; ii < 2; ++ii) {
        int idx = t + ii * 256;
        int r   = idx >> 7;
        int d   = idx & 127;
        float sum = opart[0][r][d] + opart[1][r][d]
                  + opart[2][r][d] + opart[3][r][d];
        size_t base = (((size_t)pair * 32 + c) * NREP + r) * PSTRIDE;
        ws[base + d] = sum;
        if (d == 0) { ws[base + 128] = ml[r][0]; ws[base + 129] = ml[r][1]; }
    }
}

// ---------------------------------------------------------------------------
// Kernel 2: LSE-combine nchunks chunks per (pair, rep). grid 256, block 128.
// Two-pass (no register arrays) so it works for any nchunks.
// ---------------------------------------------------------------------------
__global__ __launch_bounds__(128) void attn_reduce(
    const float* __restrict__ ws, float* __restrict__ out, int nchunks)
{
    const int idx  = blockIdx.x;      // (pair, r)
    const int pair = idx >> 2;
    const int r    = idx & 3;
    const int g    = pair >> 3;
    const int b    = pair & 7;
    const int d    = threadIdx.x;

    const size_t base0 = (((size_t)pair * nchunks) * NREP + r) * PSTRIDE;
    const size_t cstep = (size_t)NREP * PSTRIDE;

    float M = -INFINITY;
    for (int c = 0; c < nchunks; ++c)
        M = fmaxf(M, ws[base0 + c * cstep + 128]);
    float acc = 0.f, L = 0.f;
    for (int c = 0; c < nchunks; ++c) {
        size_t base = base0 + c * cstep;
        float wgt = __expf(ws[base + 128] - M);
        acc += ws[base + d] * wgt;
        L   += ws[base + 129] * wgt;
    }
    int h = g * NREP + r;
    out[(size_t)b * (NH * D) + h * D + d] = acc / L;
}

// ---------------------------------------------------------------------------
// Fallback 2 (no usable ws): one block per (head, batch), full sequence.
// ---------------------------------------------------------------------------
__global__ __launch_bounds__(256) void attn_full(
    const int*   __restrict__ input_pos,
    const float* __restrict__ q,
    const float* __restrict__ knew,
    const float* __restrict__ vnew,
    const float* __restrict__ kcache,
    const float* __restrict__ vcache,
    const float* __restrict__ mask,
    float*       __restrict__ out)
{
    const int idx = blockIdx.x;
    const int h   = idx >> 3;
    const int b   = idx & 7;
    const int g   = h >> 2;
    const int t   = threadIdx.x;
    const int wave = t >> 6, lane = t & 63, half = lane >> 5, l32 = lane & 31;
    const int pos = input_pos[0];

    __shared__ float sc[SEQ];
    __shared__ float wred[4];
    __shared__ float oacc[2][D];

    const size_t kvbase = (size_t)(g * BATCH + b) * SEQ * D;
    const float* kbase  = kcache + kvbase;
    const float* vbase  = vcache + kvbase;
    const float* mrow   = mask + (size_t)pos * SEQ;
    const float* knewr  = knew + (size_t)(g * BATCH + b) * D;
    const float* vnewr  = vnew + (size_t)(g * BATCH + b) * D;
    const float  scale  = 0.08838834764831845f;

    float4 qv = ((const float4*)(q + (size_t)(h * BATCH + b) * D))[l32];

    for (int p = 0; p < SEQ / 8; ++p) {
        int s = p * 8 + wave * 2 + half;
        const float4* krow = (s == pos) ? (const float4*)knewr
                                        : (const float4*)(kbase + (size_t)s * D);
        float4 kv = krow[l32];
        float acc = qv.x * kv.x + qv.y * kv.y + qv.z * kv.z + qv.w * kv.w;
        #pragma unroll
        for (int off = 1; off < 32; off <<= 1)
            acc += __shfl_xor(acc, off);
        if (l32 == 0) sc[s] = acc * scale + mrow[s];
    }
    __syncthreads();

    float m = -INFINITY;
    for (int s = t; s < SEQ; s += 256) m = fmaxf(m, sc[s]);
    #pragma unroll
    for (int off = 1; off < 64; off <<= 1) m = fmaxf(m, __shfl_xor(m, off));
    if (lane == 0) wred[wave] = m;
    __syncthreads();
    m = fmaxf(fmaxf(wred[0], wred[1]), fmaxf(wred[2], wred[3]));
    __syncthreads();

    float l = 0.f;
    for (int s = t; s < SEQ; s += 256) { float e = __expf(sc[s] - m); sc[s] = e; l += e; }
    #pragma unroll
    for (int off = 1; off < 64; off <<= 1) l += __shfl_xor(l, off);
    __syncthreads();
    if (lane == 0) wred[wave] = l;
    __syncthreads();
    float L = wred[0] + wred[1] + wred[2] + wred[3];

    {
        int hf = t >> 7, d = t & 127;
        float acc = 0.f;
        for (int s = hf * (SEQ / 2); s < (hf + 1) * (SEQ / 2); ++s) {
            const float* vrow = (s == pos) ? vnewr : (vbase + (size_t)s * D);
            acc += sc[s] * vrow[d];
        }
        oacc[hf][d] = acc;
    }
    __syncthreads();
    if (t < D) out[(size_t)b * (NH * D) + h * D + t] = (oacc[0][t] + oacc[1][t]) / L;
}

extern "C" void kernel_launch(void* const* d_in, const int* in_sizes, int n_in,
                              void* d_out, int out_size, void* d_ws, size_t ws_size,
                              hipStream_t stream) {
    const int*   input_pos = (const int*)  d_in[0];
    const float* q         = (const float*)d_in[1];
    const float* k         = (const float*)d_in[2];
    const float* v         = (const float*)d_in[3];
    const float* kcache    = (const float*)d_in[4];
    const float* vcache    = (const float*)d_in[5];
    const float* mask      = (const float*)d_in[6];
    float* out = (float*)d_out;

    const size_t need64 = (size_t)64 * 64 * NREP * PSTRIDE * sizeof(float);
    const size_t need32 = (size_t)64 * 32 * NREP * PSTRIDE * sizeof(float);
    if (ws_size >= need64) {
        dim3 g1(64, 64);
        attn_partial64<<<g1, 128, 0, stream>>>(input_pos, q, k, v, kcache, vcache, mask,
                                               (float*)d_ws);
        attn_reduce<<<256, 128, 0, stream>>>((const float*)d_ws, out, 64);
    } else if (ws_size >= need32) {
        dim3 g1(64, 32);
        attn_partial128<<<g1, 256, 0, stream>>>(input_pos, q, k, v, kcache, vcache, mask,
                                                (float*)d_ws);
        attn_reduce<<<256, 128, 0, stream>>>((const float*)d_ws, out, 32);
    } else {
        attn_full<<<256, 256, 0, stream>>>(input_pos, q, k, v, kcache, vcache, mask, out);
    }
}

// Round 11
// 53.364 us; speedup vs baseline: 1.6677x; 1.6677x over previous
//
#include <hip/hip_runtime.h>
#include <math.h>

#define NKV    8
#define NREP   4
#define NH     32
#define BATCH  8
#define D      128
#define SEQ    4096
#define CHUNKS 32
#define CS     128          // SEQ / CHUNKS
#define PSTRIDE 130         // 128 o + m + l per (pair,chunk,rep)

// volatile asm loads: cannot be sunk/reordered by the compiler.
// float4 is legal as an asm OUTPUT ("=v"); never use it as an input.
__device__ __forceinline__ void gload(float4& d, const float* p) {
    asm volatile("global_load_dwordx4 %0, %1, off" : "=v"(d) : "v"(p));
}
__device__ __forceinline__ void gloadf(float& d, const float* p) {
    asm volatile("global_load_dword %0, %1, off" : "=v"(d) : "v"(p));
}

// counted wait + scheduler fence (rule 18: sched_barrier stops hipcc from
// hoisting register-only consumers above the waitcnt)
#define VMWAIT(n) do { \
        asm volatile("s_waitcnt vmcnt(" #n ")" ::: "memory"); \
        __builtin_amdgcn_sched_barrier(0); \
    } while (0)

// ---------------------------------------------------------------------------
// Kernel 1: partial attention per (pair = g*8+b, chunk of 128 rows).
// grid (64, 32), block 256 (4 waves). R5 structure + asm software pipeline:
// scores = 8 iters, 2 loads/iter, depth 4; PV = 16 iters, 1 load/iter,
// depth 8, issued BEFORE softmax and carried across a raw s_barrier.
// ALL global loads in this kernel go through volatile asm, so the only
// vmcnt arithmetic is ours.
// ---------------------------------------------------------------------------
__global__ __launch_bounds__(256, 4) void attn_partial(
    const int*   __restrict__ input_pos,
    const float* __restrict__ q,
    const float* __restrict__ knew,
    const float* __restrict__ vnew,
    const float* __restrict__ kcache,
    const float* __restrict__ vcache,
    const float* __restrict__ mask,
    float*       __restrict__ ws)
{
    const int pair = blockIdx.x;      // g*8 + b
    const int c    = blockIdx.y;
    const int g    = pair >> 3;
    const int b    = pair & 7;
    const int t    = threadIdx.x;
    const int w    = t >> 6;          // wave id
    const int lane = t & 63;
    const int p4   = lane >> 4;       // row within 4-row group (scores)
    const int l16  = lane & 15;       // 8-float segment (scores)
    const int half = lane >> 5;       // row parity (PV)
    const int l32  = lane & 31;       // float4 d-slice (PV)
    const int pos  = input_pos[0];

    __shared__ float sc[NREP][CS];        // raw scores, then e-values
    __shared__ float ml[NREP][2];         // per-rep (max, sum)
    __shared__ float opart[4][NREP][D];   // per-wave PV partials (8 KiB)

    const float  scale  = 0.08838834764831845f;   // 1/sqrt(128)
    const size_t kvbase = (size_t)(g * BATCH + b) * SEQ * D;
    const float* kbase  = kcache + kvbase;
    const float* vbase  = vcache + kvbase;
    const float* mrow   = mask + (size_t)pos * SEQ;
    const float* knewr  = knew + (size_t)(g * BATCH + b) * D;
    const float* vnewr  = vnew + (size_t)(g * BATCH + b) * D;
    const int    s0     = c * CS;
    const int    rowbase = w * 32;

    // ---- prologue: q fragments + mask value, all via asm loads ----
    float4 qv[NREP][2];
    float  mreg;
    #pragma unroll
    for (int r = 0; r < NREP; ++r) {
        const float* qr = q + ((size_t)(g * NREP + r) * BATCH + b) * D + l16 * 8;
        gload(qv[r][0], qr);
        gload(qv[r][1], qr + 4);
    }
    gloadf(mreg, mrow + s0 + rowbase + (lane & 31));
    VMWAIT(0);                        // q + mask resident

    float mval[8];
    #pragma unroll
    for (int i = 0; i < 8; ++i)
        mval[i] = __shfl(mreg, i * 4 + p4);

    // ---- scores: software pipeline, depth 4 (8 loads in flight) ----
    float4 kd[4][2];

#define SC_ISSUE(i) do { \
        const int s_ = s0 + rowbase + (i) * 4 + p4; \
        const float* kr_ = ((s_ == pos) ? knewr : (kbase + (size_t)s_ * D)) + l16 * 8; \
        gload(kd[(i) & 3][0], kr_); \
        gload(kd[(i) & 3][1], kr_ + 4); \
    } while (0)

#define SC_CONSUME(i, n) do { \
        VMWAIT(n); \
        const float4 k0 = kd[(i) & 3][0], k1 = kd[(i) & 3][1]; \
        float acc[NREP]; \
        _Pragma("unroll") \
        for (int r = 0; r < NREP; ++r) { \
            float a; \
            a = k0.x * qv[r][0].x; \
            a = fmaf(k0.y, qv[r][0].y, a); \
            a = fmaf(k0.z, qv[r][0].z, a); \
            a = fmaf(k0.w, qv[r][0].w, a); \
            a = fmaf(k1.x, qv[r][1].x, a); \
            a = fmaf(k1.y, qv[r][1].y, a); \
            a = fmaf(k1.z, qv[r][1].z, a); \
            a = fmaf(k1.w, qv[r][1].w, a); \
            acc[r] = a; \
        } \
        _Pragma("unroll") \
        for (int off = 1; off < 16; off <<= 1) { \
            _Pragma("unroll") \
            for (int r = 0; r < NREP; ++r) \
                acc[r] += __shfl_xor(acc[r], off); \
        } \
        if (l16 == 0) { \
            const int sl_ = rowbase + (i) * 4 + p4; \
            _Pragma("unroll") \
            for (int r = 0; r < NREP; ++r) \
                sc[r][sl_] = fmaf(acc[r], scale, mval[(i)]); \
        } \
    } while (0)

    SC_ISSUE(0); SC_ISSUE(1); SC_ISSUE(2); SC_ISSUE(3);
    SC_CONSUME(0, 6); SC_ISSUE(4);
    SC_CONSUME(1, 6); SC_ISSUE(5);
    SC_CONSUME(2, 6); SC_ISSUE(6);
    SC_CONSUME(3, 6); SC_ISSUE(7);
    SC_CONSUME(4, 6);
    SC_CONSUME(5, 4);
    SC_CONSUME(6, 2);
    SC_CONSUME(7, 0);

    __syncthreads();                  // vmcnt already 0 here

    // ---- issue first 8 V loads; they stay in flight across softmax ----
    float4 vd[8];

#define PV_ISSUE(it) do { \
        const int s_ = s0 + rowbase + (it) * 2 + half; \
        const float* vr_ = ((s_ == pos) ? vnewr : (vbase + (size_t)s_ * D)) + l32 * 4; \
        gload(vd[(it) & 7], vr_); \
    } while (0)

    PV_ISSUE(0); PV_ISSUE(1); PV_ISSUE(2); PV_ISSUE(3);
    PV_ISSUE(4); PV_ISSUE(5); PV_ISSUE(6); PV_ISSUE(7);

    // ---- softmax: wave w owns rep r = w (LDS + shuffles only: lgkmcnt) ----
    {
        const int r = w;
        float v0 = sc[r][lane];
        float v1 = sc[r][lane + 64];
        float m  = fmaxf(v0, v1);
        #pragma unroll
        for (int off = 1; off < 64; off <<= 1)
            m = fmaxf(m, __shfl_xor(m, off));
        float e0 = __expf(v0 - m);
        float e1 = __expf(v1 - m);
        sc[r][lane]      = e0;
        sc[r][lane + 64] = e1;
        float l = e0 + e1;
        #pragma unroll
        for (int off = 1; off < 64; off <<= 1)
            l += __shfl_xor(l, off);
        if (lane == 0) { ml[r][0] = m; ml[r][1] = l; }
    }
    // barrier WITHOUT vmcnt drain: LDS-only wait + raw barrier
    asm volatile("s_waitcnt lgkmcnt(0)" ::: "memory");
    __builtin_amdgcn_sched_barrier(0);
    __builtin_amdgcn_s_barrier();

    // ---- PV: depth-8 pipeline ----
    float4 oacc[NREP];
    #pragma unroll
    for (int r = 0; r < NREP; ++r) oacc[r] = make_float4(0.f, 0.f, 0.f, 0.f);

#define PV_CONSUME(it, n) do { \
        VMWAIT(n); \
        const float4 v4 = vd[(it) & 7]; \
        const int sl_ = rowbase + (it) * 2 + half; \
        _Pragma("unroll") \
        for (int r = 0; r < NREP; ++r) { \
            const float pr = sc[r][sl_]; \
            oacc[r].x = fmaf(pr, v4.x, oacc[r].x); \
            oacc[r].y = fmaf(pr, v4.y, oacc[r].y); \
            oacc[r].z = fmaf(pr, v4.z, oacc[r].z); \
            oacc[r].w = fmaf(pr, v4.w, oacc[r].w); \
        } \
    } while (0)

    PV_CONSUME(0, 7);  PV_ISSUE(8);
    PV_CONSUME(1, 7);  PV_ISSUE(9);
    PV_CONSUME(2, 7);  PV_ISSUE(10);
    PV_CONSUME(3, 7);  PV_ISSUE(11);
    PV_CONSUME(4, 7);  PV_ISSUE(12);
    PV_CONSUME(5, 7);  PV_ISSUE(13);
    PV_CONSUME(6, 7);  PV_ISSUE(14);
    PV_CONSUME(7, 7);  PV_ISSUE(15);
    PV_CONSUME(8, 7);
    PV_CONSUME(9, 6);
    PV_CONSUME(10, 5);
    PV_CONSUME(11, 4);
    PV_CONSUME(12, 3);
    PV_CONSUME(13, 2);
    PV_CONSUME(14, 1);
    PV_CONSUME(15, 0);

    #pragma unroll
    for (int r = 0; r < NREP; ++r) {
        oacc[r].x += __shfl_xor(oacc[r].x, 32);
        oacc[r].y += __shfl_xor(oacc[r].y, 32);
        oacc[r].z += __shfl_xor(oacc[r].z, 32);
        oacc[r].w += __shfl_xor(oacc[r].w, 32);
    }
    if (half == 0) {
        #pragma unroll
        for (int r = 0; r < NREP; ++r)
            *(float4*)&opart[w][r][l32 * 4] = oacc[r];
    }
    asm volatile("s_waitcnt lgkmcnt(0)" ::: "memory");
    __builtin_amdgcn_sched_barrier(0);
    __builtin_amdgcn_s_barrier();

    // ---- final: sum the 4 wave partials, write workspace ----
    #pragma unroll
    for (int ii = 0; ii < 2; ++ii) {
        int idx = t + ii * 256;       // 0..511 -> (r, d)
        int r   = idx >> 7;
        int d   = idx & 127;
        float sum = opart[0][r][d] + opart[1][r][d]
                  + opart[2][r][d] + opart[3][r][d];
        size_t base = (((size_t)pair * CHUNKS + c) * NREP + r) * PSTRIDE;
        ws[base + d] = sum;
        if (d == 0) { ws[base + 128] = ml[r][0]; ws[base + 129] = ml[r][1]; }
    }
}

// ---------------------------------------------------------------------------
// Kernel 2: LSE-combine the 32 chunks per (pair, rep). grid 256, block 128.
// ---------------------------------------------------------------------------
__global__ __launch_bounds__(128) void attn_reduce(
    const float* __restrict__ ws, float* __restrict__ out)
{
    const int idx  = blockIdx.x;      // (pair, r)
    const int pair = idx >> 2;
    const int r    = idx & 3;
    const int g    = pair >> 3;
    const int b    = pair & 7;
    const int d    = threadIdx.x;

    float mv[CHUNKS], lv[CHUNKS];
    float M = -INFINITY;
    #pragma unroll
    for (int c = 0; c < CHUNKS; ++c) {
        size_t base = (((size_t)pair * CHUNKS + c) * NREP + r) * PSTRIDE;
        float2 t = *(const float2*)&ws[base + 128];
        mv[c] = t.x; lv[c] = t.y;
        M = fmaxf(M, t.x);
    }
    float acc = 0.f, L = 0.f;
    #pragma unroll
    for (int c = 0; c < CHUNKS; ++c) {
        size_t base = (((size_t)pair * CHUNKS + c) * NREP + r) * PSTRIDE;
        float wgt = __expf(mv[c] - M);
        acc += ws[base + d] * wgt;
        L   += lv[c] * wgt;
    }
    int h = g * NREP + r;
    out[(size_t)b * (NH * D) + h * D + d] = acc / L;
}

// ---------------------------------------------------------------------------
// Fallback (ws too small): one block per (head, batch), full sequence.
// ---------------------------------------------------------------------------
__global__ __launch_bounds__(256) void attn_full(
    const int*   __restrict__ input_pos,
    const float* __restrict__ q,
    const float* __restrict__ knew,
    const float* __restrict__ vnew,
    const float* __restrict__ kcache,
    const float* __restrict__ vcache,
    const float* __restrict__ mask,
    float*       __restrict__ out)
{
    const int idx = blockIdx.x;       // h*8 + b
    const int h   = idx >> 3;
    const int b   = idx & 7;
    const int g   = h >> 2;
    const int t   = threadIdx.x;
    const int wave = t >> 6, lane = t & 63, half = lane >> 5, l32 = lane & 31;
    const int pos = input_pos[0];

    __shared__ float sc[SEQ];         // 16 KB
    __shared__ float wred[4];
    __shared__ float oacc[2][D];

    const size_t kvbase = (size_t)(g * BATCH + b) * SEQ * D;
    const float* kbase  = kcache + kvbase;
    const float* vbase  = vcache + kvbase;
    const float* mrow   = mask + (size_t)pos * SEQ;
    const float* knewr  = knew + (size_t)(g * BATCH + b) * D;
    const float* vnewr  = vnew + (size_t)(g * BATCH + b) * D;
    const float  scale  = 0.08838834764831845f;

    float4 qv = ((const float4*)(q + (size_t)(h * BATCH + b) * D))[l32];

    for (int p = 0; p < SEQ / 8; ++p) {
        int s = p * 8 + wave * 2 + half;
        const float4* krow = (s == pos) ? (const float4*)knewr
                                        : (const float4*)(kbase + (size_t)s * D);
        float4 kv = krow[l32];
        float acc = qv.x * kv.x + qv.y * kv.y + qv.z * kv.z + qv.w * kv.w;
        #pragma unroll
        for (int off = 1; off < 32; off <<= 1)
            acc += __shfl_xor(acc, off);
        if (l32 == 0) sc[s] = acc * scale + mrow[s];
    }
    __syncthreads();

    float m = -INFINITY;
    for (int s = t; s < SEQ; s += 256) m = fmaxf(m, sc[s]);
    #pragma unroll
    for (int off = 1; off < 64; off <<= 1) m = fmaxf(m, __shfl_xor(m, off));
    if (lane == 0) wred[wave] = m;
    __syncthreads();
    m = fmaxf(fmaxf(wred[0], wred[1]), fmaxf(wred[2], wred[3]));
    __syncthreads();

    float l = 0.f;
    for (int s = t; s < SEQ; s += 256) { float e = __expf(sc[s] - m); sc[s] = e; l += e; }
    #pragma unroll
    for (int off = 1; off < 64; off <<= 1) l += __shfl_xor(l, off);
    __syncthreads();
    if (lane == 0) wred[wave] = l;
    __syncthreads();
    float L = wred[0] + wred[1] + wred[2] + wred[3];

    {
        int hf = t >> 7, d = t & 127;
        float acc = 0.f;
        for (int s = hf * (SEQ / 2); s < (hf + 1) * (SEQ / 2); ++s) {
            const float* vrow = (s == pos) ? vnewr : (vbase + (size_t)s * D);
            acc += sc[s] * vrow[d];
        }
        oacc[hf][d] = acc;
    }
    __syncthreads();
    if (t < D) out[(size_t)b * (NH * D) + h * D + t] = (oacc[0][t] + oacc[1][t]) / L;
}

extern "C" void kernel_launch(void* const* d_in, const int* in_sizes, int n_in,
                              void* d_out, int out_size, void* d_ws, size_t ws_size,
                              hipStream_t stream) {
    const int*   input_pos = (const int*)  d_in[0];
    const float* q         = (const float*)d_in[1];
    const float* k         = (const float*)d_in[2];
    const float* v         = (const float*)d_in[3];
    const float* kcache    = (const float*)d_in[4];
    const float* vcache    = (const float*)d_in[5];
    const float* mask      = (const float*)d_in[6];
    float* out = (float*)d_out;

    const size_t need = (size_t)64 * CHUNKS * NREP * PSTRIDE * sizeof(float);
    if (ws_size >= need) {
        dim3 g1(64, CHUNKS);
        attn_partial<<<g1, 256, 0, stream>>>(input_pos, q, k, v, kcache, vcache, mask,
                                             (float*)d_ws);
        attn_reduce<<<256, 128, 0, stream>>>((const float*)d_ws, out);
    } else {
        attn_full<<<256, 256, 0, stream>>>(input_pos, q, k, v, kcache, vcache, mask, out);
    }
}